// Round 3
// baseline (294.534 us; speedup 1.0000x reference)
//
#include <hip/hip_runtime.h>
#include <hip/hip_fp16.h>

typedef _Float16 half8_t __attribute__((ext_vector_type(8)));
typedef _Float16 half4_t __attribute__((ext_vector_type(4)));
typedef float f32x4 __attribute__((ext_vector_type(4)));

#define TILE 128
#define BK 32

__device__ __forceinline__ void gload_lds16(const void* g, void* l) {
    __builtin_amdgcn_global_load_lds(
        (const __attribute__((address_space(1))) void*)g,
        (__attribute__((address_space(3))) void*)l,
        16, 0, 0);
}

// ---------------- x fp32 -> fp16 ----------------
__global__ __launch_bounds__(256) void cvt_f32_f16_kernel(
    const float* __restrict__ x, _Float16* __restrict__ xh, int n) {
    int i = (blockIdx.x * 256 + threadIdx.x) * 4;
    if (i < n) {
        float4 v = *(const float4*)(x + i);
        half4_t h;
        h[0] = (_Float16)v.x; h[1] = (_Float16)v.y;
        h[2] = (_Float16)v.z; h[3] = (_Float16)v.w;
        *(half4_t*)(xh + i) = h;
    }
}

// ---------------- PQ quantize: weight -> wq (fp16) ----------------
// v3: NG=2 (16 waves/CU), codebook in LDS, explicit 2-deep register
// prefetch pipeline so LDS latency overlaps the FMA chains.
// score = |c|^2 - 2 g.c (gap-identical to |g-c|^2); fp64 near-tie rescan.
__global__ __launch_bounds__(256) void pq_quant_kernel(
    const float* __restrict__ W, const float* __restrict__ cbg,
    const float* __restrict__ rs, _Float16* __restrict__ wq,
    int groups_per_row, int n_groups) {
    __shared__ float scb[256 * 8];
    __shared__ float c2s[256];
    int tid = threadIdx.x;
    // stage codebook (8 KB) into LDS
    for (int i = tid; i < 512; i += 256)
        ((float4*)scb)[i] = ((const float4*)cbg)[i];
    __syncthreads();
    {   // |c|^2 per codeword (one per thread)
        const float* cp = scb + tid * 8;
        float4 a = *(const float4*)cp;
        float4 b = *(const float4*)(cp + 4);
        float s = a.x * a.x;
        s = fmaf(a.y, a.y, s); s = fmaf(a.z, a.z, s); s = fmaf(a.w, a.w, s);
        s = fmaf(b.x, b.x, s); s = fmaf(b.y, b.y, s); s = fmaf(b.z, b.z, s);
        s = fmaf(b.w, b.w, s);
        c2s[tid] = s;
    }
    __syncthreads();

    const int NG = 2;
    int gbase = blockIdx.x * (256 * NG) + tid;

    float gv[NG][8];
    float rscale[NG];
#pragma unroll
    for (int j = 0; j < NG; j++) {
        int g = gbase + j * 256;
        int o = g / groups_per_row;
        float rsv = rs[o];
        rscale[j] = rsv;
        float rinv = 1.0f / rsv;
        const float* wp = W + (size_t)g * 8;
        float4 w0 = *(const float4*)wp;
        float4 w1 = *(const float4*)(wp + 4);
        gv[j][0] = w0.x * rinv; gv[j][1] = w0.y * rinv;
        gv[j][2] = w0.z * rinv; gv[j][3] = w0.w * rinv;
        gv[j][4] = w1.x * rinv; gv[j][5] = w1.y * rinv;
        gv[j][6] = w1.z * rinv; gv[j][7] = w1.w * rinv;
    }

    float best[NG], sec[NG];
    int bidx[NG];
#pragma unroll
    for (int j = 0; j < NG; j++) { best[j] = 1e30f; sec[j] = 1e30f; bidx[j] = 0; }

    // 2-deep software pipeline over codewords
    float4 a0 = *(const float4*)&scb[0], a1 = *(const float4*)&scb[4];
    float4 b0 = *(const float4*)&scb[8], b1 = *(const float4*)&scb[12];
    float cA = c2s[0], cB = c2s[1];

    for (int k = 0; k < 256; k += 2) {
        int kn2 = (k + 2) & 255;
        int kn3 = (k + 3) & 255;
        float4 na0 = *(const float4*)&scb[kn2 * 8];
        float4 na1 = *(const float4*)&scb[kn2 * 8 + 4];
        float nA = c2s[kn2];
        float4 nb0 = *(const float4*)&scb[kn3 * 8];
        float4 nb1 = *(const float4*)&scb[kn3 * 8 + 4];
        float nB = c2s[kn3];

#pragma unroll
        for (int j = 0; j < NG; j++) {
            float dot = gv[j][0] * a0.x;
            dot = fmaf(gv[j][1], a0.y, dot);
            dot = fmaf(gv[j][2], a0.z, dot);
            dot = fmaf(gv[j][3], a0.w, dot);
            dot = fmaf(gv[j][4], a1.x, dot);
            dot = fmaf(gv[j][5], a1.y, dot);
            dot = fmaf(gv[j][6], a1.z, dot);
            dot = fmaf(gv[j][7], a1.w, dot);
            float s = fmaf(dot, -2.0f, cA);
            bool cond = s < best[j];
            sec[j] = __builtin_amdgcn_fmed3f(s, best[j], sec[j]);
            best[j] = fminf(best[j], s);
            bidx[j] = cond ? k : bidx[j];
        }
#pragma unroll
        for (int j = 0; j < NG; j++) {
            float dot = gv[j][0] * b0.x;
            dot = fmaf(gv[j][1], b0.y, dot);
            dot = fmaf(gv[j][2], b0.z, dot);
            dot = fmaf(gv[j][3], b0.w, dot);
            dot = fmaf(gv[j][4], b1.x, dot);
            dot = fmaf(gv[j][5], b1.y, dot);
            dot = fmaf(gv[j][6], b1.z, dot);
            dot = fmaf(gv[j][7], b1.w, dot);
            float s = fmaf(dot, -2.0f, cB);
            bool cond = s < best[j];
            sec[j] = __builtin_amdgcn_fmed3f(s, best[j], sec[j]);
            best[j] = fminf(best[j], s);
            bidx[j] = cond ? (k + 1) : bidx[j];
        }
        a0 = na0; a1 = na1; cA = nA;
        b0 = nb0; b1 = nb1; cB = nB;
    }

#pragma unroll
    for (int j = 0; j < NG; j++) {
        int g = gbase + j * 256;
        if (g >= n_groups) continue;
        int bi = bidx[j];
        // near-tie: re-scan in fp64 so argmin matches the fp64 reference
        if (sec[j] - best[j] < 5e-4f) {
            const float* wp = W + (size_t)g * 8;
            double gd[8];
            double rsd = (double)rscale[j];
            for (int i = 0; i < 8; i++) gd[i] = (double)wp[i] / rsd;
            double bestd = 1e300;
            int bi2 = 0;
            for (int k = 0; k < 256; k++) {
                const float* c = scb + k * 8;
                double acc = 0.0;
                for (int i = 0; i < 8; i++) {
                    double d = gd[i] - (double)c[i];
                    acc = fma(d, d, acc);
                }
                if (acc < bestd) { bestd = acc; bi2 = k; }
            }
            bi = bi2;
        }
        const float* c = scb + bi * 8;
        float rsv = rscale[j];
        half8_t outv;
#pragma unroll
        for (int i = 0; i < 8; i++) outv[i] = (_Float16)(c[i] * rsv);
        *(half8_t*)(wq + (size_t)g * 8) = outv;
    }
}

// ---------------- GEMM: C[M][N] = A[M][K] @ B[N][K]^T + bias ----------------
// fp16 MFMA 16x16x32, 128x128 block tile, 4 waves each 64x64, BK=32,
// global_load_lds width-16 staging. Split-K=2 via gridDim.z + fp32 atomicAdd
// (d_out zeroed by memsetAsync; bias added by kz==0 blocks).
__global__ __launch_bounds__(256) void gemm_f16_kernel(
    const _Float16* __restrict__ A, const _Float16* __restrict__ B,
    const float* __restrict__ bias, float* __restrict__ C,
    int M, int N, int K) {
    __shared__ _Float16 sA[TILE * BK];
    __shared__ _Float16 sB[TILE * BK];
    int tid = threadIdx.x;
    int wave = tid >> 6, lane = tid & 63;
    int wm = wave >> 1, wn = wave & 1;
    int bm = blockIdx.y * TILE, bn = blockIdx.x * TILE;
    int kz = blockIdx.z;
    int Khalf = K >> 1;
    int kbase = kz * Khalf;

    f32x4 acc[4][4] = {};

    int srow = wave * 16 + (lane >> 2);
    int skc = (lane & 3) * 8;

    const int kIters = Khalf / BK;
    for (int kt = 0; kt < kIters; kt++) {
        int k0 = kbase + kt * BK;
        __syncthreads();
#pragma unroll
        for (int j = 0; j < 2; j++) {
            int row = j * 64 + srow;
            int ldsbase = (j * 64 + wave * 16) * BK;
            gload_lds16(A + (size_t)(bm + row) * K + k0 + skc, &sA[ldsbase]);
            gload_lds16(B + (size_t)(bn + row) * K + k0 + skc, &sB[ldsbase]);
        }
        __syncthreads();

        half8_t a[4], b[4];
#pragma unroll
        for (int mt = 0; mt < 4; mt++)
            a[mt] = *(const half8_t*)&sA[(wm * 64 + mt * 16 + (lane & 15)) * BK + (lane >> 4) * 8];
#pragma unroll
        for (int nt = 0; nt < 4; nt++)
            b[nt] = *(const half8_t*)&sB[(wn * 64 + nt * 16 + (lane & 15)) * BK + (lane >> 4) * 8];
#pragma unroll
        for (int mt = 0; mt < 4; mt++)
#pragma unroll
            for (int nt = 0; nt < 4; nt++)
                acc[mt][nt] = __builtin_amdgcn_mfma_f32_16x16x32_f16(
                    a[mt], b[nt], acc[mt][nt], 0, 0, 0);
    }

    int col_base = bn + wn * 64;
    int row_base = bm + wm * 64;
#pragma unroll
    for (int nt = 0; nt < 4; nt++) {
        int col = col_base + nt * 16 + (lane & 15);
        float bv = (kz == 0) ? bias[col] : 0.0f;
#pragma unroll
        for (int mt = 0; mt < 4; mt++) {
            int r0 = row_base + mt * 16 + (lane >> 4) * 4;
#pragma unroll
            for (int r = 0; r < 4; r++)
                atomicAdd(&C[(size_t)(r0 + r) * N + col], acc[mt][nt][r] + bv);
        }
    }
}

extern "C" void kernel_launch(void* const* d_in, const int* in_sizes, int n_in,
                              void* d_out, int out_size, void* d_ws, size_t ws_size,
                              hipStream_t stream) {
    const float* x        = (const float*)d_in[0];
    const float* weight   = (const float*)d_in[1];
    const float* codebook = (const float*)d_in[2];
    const float* rowscale = (const float*)d_in[3];
    const float* bias     = (const float*)d_in[4];
    float* out = (float*)d_out;

    int O = in_sizes[3];          // row_scale has O elements
    int I = in_sizes[1] / O;      // weight is O*I
    int M = in_sizes[0] / I;      // x is (B*S)*I
    const int D = 8;
    int n_groups = O * I / D;

    _Float16* xh = (_Float16*)d_ws;
    _Float16* wq = (_Float16*)((char*)d_ws + (size_t)M * I * sizeof(_Float16));

    int n_x = M * I;
    cvt_f32_f16_kernel<<<(n_x / 4 + 255) / 256, 256, 0, stream>>>(x, xh, n_x);
    pq_quant_kernel<<<(n_groups + 511) / 512, 256, 0, stream>>>(
        weight, codebook, rowscale, wq, I / D, n_groups);
    hipMemsetAsync(out, 0, (size_t)out_size * sizeof(float), stream);
    gemm_f16_kernel<<<dim3(O / TILE, M / TILE, 2), 256, 0, stream>>>(
        xh, wq, bias, out, M, O, I);
}

// Round 4
// 226.444 us; speedup vs baseline: 1.3007x; 1.3007x over previous
//
#include <hip/hip_runtime.h>
#include <hip/hip_fp16.h>

typedef _Float16 half8_t __attribute__((ext_vector_type(8)));
typedef _Float16 half4_t __attribute__((ext_vector_type(4)));
typedef float f32x4 __attribute__((ext_vector_type(4)));

#define TILE 128
#define BK 32

__device__ __forceinline__ void gload_lds16(const void* g, void* l) {
    __builtin_amdgcn_global_load_lds(
        (const __attribute__((address_space(1))) void*)g,
        (__attribute__((address_space(3))) void*)l,
        16, 0, 0);
}

// ---------------- x fp32 -> fp16 (+ |c|^2 precompute in block 0) ----------------
__global__ __launch_bounds__(256) void cvt_f32_f16_kernel(
    const float* __restrict__ x, _Float16* __restrict__ xh, int n,
    const float* __restrict__ cb, float* __restrict__ c2) {
    int i = (blockIdx.x * 256 + threadIdx.x) * 4;
    if (i < n) {
        float4 v = *(const float4*)(x + i);
        half4_t h;
        h[0] = (_Float16)v.x; h[1] = (_Float16)v.y;
        h[2] = (_Float16)v.z; h[3] = (_Float16)v.w;
        *(half4_t*)(xh + i) = h;
    }
    if (blockIdx.x == 0) {
        // |c|^2 for each of the 256 codewords (one per thread)
        const float* cp = cb + threadIdx.x * 8;
        float4 a = *(const float4*)cp;
        float4 b = *(const float4*)(cp + 4);
        float s = a.x * a.x;
        s = fmaf(a.y, a.y, s); s = fmaf(a.z, a.z, s); s = fmaf(a.w, a.w, s);
        s = fmaf(b.x, b.x, s); s = fmaf(b.y, b.y, s); s = fmaf(b.z, b.z, s);
        s = fmaf(b.w, b.w, s);
        c2[threadIdx.x] = s;
    }
}

// ---------------- PQ quantize: weight -> wq (fp16) ----------------
// v4: 1 group/thread (2048 blocks -> 8 blocks/CU), codebook + |c|^2 via
// UNIFORM SCALAR loads (s_load; no LDS, no per-lane VMEM in the hot loop).
// score = |c|^2 - 2 g.c (argmin-equivalent to |g-c|^2). Track top-2 values
// AND indices; near-tie (gap < 5e-4) resolved by exact fp64 compare of just
// the two candidates (same semantics as the full fp64 rescan used in R1-R3).
__global__ __launch_bounds__(256) void pq_quant_kernel(
    const float* __restrict__ W, const float* __restrict__ cb,
    const float* __restrict__ c2g, const float* __restrict__ rs,
    _Float16* __restrict__ wq, int groups_per_row) {
    int tid = threadIdx.x;
    int g = blockIdx.x * 256 + tid;
    int o = g / groups_per_row;
    float rsv = rs[o];
    float rinv = 1.0f / rsv;
    const float* wp = W + (size_t)g * 8;
    float4 w0 = *(const float4*)wp;
    float4 w1 = *(const float4*)(wp + 4);
    float g0 = w0.x * rinv, g1 = w0.y * rinv, g2 = w0.z * rinv, g3 = w0.w * rinv;
    float g4 = w1.x * rinv, g5 = w1.y * rinv, g6 = w1.z * rinv, g7 = w1.w * rinv;

    float best = 1e30f, sec = 1e30f;
    int bidx = 0, sidx = 0;
#pragma unroll 4
    for (int k = 0; k < 256; k++) {
        const float* cp = cb + k * 8;               // uniform -> s_load_dwordx8
        float c0 = cp[0], c1 = cp[1], c2v = cp[2], c3 = cp[3];
        float c4 = cp[4], c5 = cp[5], c6 = cp[6], c7 = cp[7];
        float cc = c2g[k];                          // uniform -> s_load_dword
        float dot = g0 * c0;
        dot = fmaf(g1, c1, dot);
        dot = fmaf(g2, c2v, dot);
        dot = fmaf(g3, c3, dot);
        dot = fmaf(g4, c4, dot);
        dot = fmaf(g5, c5, dot);
        dot = fmaf(g6, c6, dot);
        dot = fmaf(g7, c7, dot);
        float s = fmaf(dot, -2.0f, cc);             // |c|^2 - 2 g.c
        bool lb = s < best;
        bool ls = s < sec;
        sidx = lb ? bidx : (ls ? k : sidx);         // uses OLD bidx
        sec = __builtin_amdgcn_fmed3f(s, best, sec);
        bidx = lb ? k : bidx;
        best = fminf(s, best);
    }

    // near-tie: exact fp64 compare of the two candidates (matches a fp64
    // reference argmin; first-occurrence wins on exact fp64 tie)
    if (sec - best < 5e-4f) {
        double gd[8];
        double rsd = (double)rsv;
#pragma unroll
        for (int i = 0; i < 8; i++) gd[i] = (double)wp[i] / rsd;
        const float* cbp = cb + bidx * 8;
        const float* csp = cb + sidx * 8;
        double db = 0.0, ds = 0.0;
#pragma unroll
        for (int i = 0; i < 8; i++) {
            double d = gd[i] - (double)cbp[i];
            db = fma(d, d, db);
        }
#pragma unroll
        for (int i = 0; i < 8; i++) {
            double d = gd[i] - (double)csp[i];
            ds = fma(d, d, ds);
        }
        if (ds < db || (ds == db && sidx < bidx)) bidx = sidx;
    }

    const float* c = cb + bidx * 8;                 // per-lane gather (L1-hot)
    half8_t outv;
#pragma unroll
    for (int i = 0; i < 8; i++) outv[i] = (_Float16)(c[i] * rsv);
    *(half8_t*)(wq + (size_t)g * 8) = outv;
}

// ---------------- GEMM: C[M][N] = A[M][K] @ B[N][K]^T (+ bias) ----------------
// fp16 MFMA 16x16x32, 128x128 tile, 4 waves each 64x64, BK=32,
// global_load_lds width-16 staging. Optional split-K via gridDim.z:
// kz==0 stores to C0 (+bias), kz==1 stores to C1 partial (no atomics).
__global__ __launch_bounds__(256) void gemm_f16_kernel(
    const _Float16* __restrict__ A, const _Float16* __restrict__ B,
    const float* __restrict__ bias, float* __restrict__ C0,
    float* __restrict__ C1, int M, int N, int K, int Ksplit) {
    __shared__ _Float16 sA[TILE * BK];
    __shared__ _Float16 sB[TILE * BK];
    int tid = threadIdx.x;
    int wave = tid >> 6, lane = tid & 63;
    int wm = wave >> 1, wn = wave & 1;
    int bm = blockIdx.y * TILE, bn = blockIdx.x * TILE;
    int kz = blockIdx.z;
    int kbase = kz * Ksplit;

    f32x4 acc[4][4] = {};

    int srow = wave * 16 + (lane >> 2);
    int skc = (lane & 3) * 8;

    const int kIters = Ksplit / BK;
    for (int kt = 0; kt < kIters; kt++) {
        int k0 = kbase + kt * BK;
        __syncthreads();
#pragma unroll
        for (int j = 0; j < 2; j++) {
            int row = j * 64 + srow;
            int ldsbase = (j * 64 + wave * 16) * BK;
            gload_lds16(A + (size_t)(bm + row) * K + k0 + skc, &sA[ldsbase]);
            gload_lds16(B + (size_t)(bn + row) * K + k0 + skc, &sB[ldsbase]);
        }
        __syncthreads();

        half8_t a[4], b[4];
#pragma unroll
        for (int mt = 0; mt < 4; mt++)
            a[mt] = *(const half8_t*)&sA[(wm * 64 + mt * 16 + (lane & 15)) * BK + (lane >> 4) * 8];
#pragma unroll
        for (int nt = 0; nt < 4; nt++)
            b[nt] = *(const half8_t*)&sB[(wn * 64 + nt * 16 + (lane & 15)) * BK + (lane >> 4) * 8];
#pragma unroll
        for (int mt = 0; mt < 4; mt++)
#pragma unroll
            for (int nt = 0; nt < 4; nt++)
                acc[mt][nt] = __builtin_amdgcn_mfma_f32_16x16x32_f16(
                    a[mt], b[nt], acc[mt][nt], 0, 0, 0);
    }

    float* C = (kz == 0) ? C0 : C1;
    int col_base = bn + wn * 64;
    int row_base = bm + wm * 64;
#pragma unroll
    for (int nt = 0; nt < 4; nt++) {
        int col = col_base + nt * 16 + (lane & 15);
        float bv = (kz == 0) ? bias[col] : 0.0f;
#pragma unroll
        for (int mt = 0; mt < 4; mt++) {
            int r0 = row_base + mt * 16 + (lane >> 4) * 4;
#pragma unroll
            for (int r = 0; r < 4; r++)
                C[(size_t)(r0 + r) * N + col] = acc[mt][nt][r] + bv;
        }
    }
}

// ---------------- out += partial ----------------
__global__ __launch_bounds__(256) void reduce_add_kernel(
    float* __restrict__ out, const float* __restrict__ part, int n) {
    int i = (blockIdx.x * 256 + threadIdx.x) * 4;
    if (i < n) {
        float4 a = *(const float4*)(out + i);
        float4 b = *(const float4*)(part + i);
        a.x += b.x; a.y += b.y; a.z += b.z; a.w += b.w;
        *(float4*)(out + i) = a;
    }
}

extern "C" void kernel_launch(void* const* d_in, const int* in_sizes, int n_in,
                              void* d_out, int out_size, void* d_ws, size_t ws_size,
                              hipStream_t stream) {
    const float* x        = (const float*)d_in[0];
    const float* weight   = (const float*)d_in[1];
    const float* codebook = (const float*)d_in[2];
    const float* rowscale = (const float*)d_in[3];
    const float* bias     = (const float*)d_in[4];
    float* out = (float*)d_out;

    int O = in_sizes[3];          // row_scale has O elements
    int I = in_sizes[1] / O;      // weight is O*I
    int M = in_sizes[0] / I;      // x is (B*S)*I
    const int D = 8;
    int n_groups = O * I / D;

    size_t off = 0;
    _Float16* xh = (_Float16*)d_ws;              off += (size_t)M * I * sizeof(_Float16);
    _Float16* wq = (_Float16*)((char*)d_ws + off); off += (size_t)O * I * sizeof(_Float16);
    float* c2   = (float*)((char*)d_ws + off);   off += 4096;  // 256 floats, padded
    float* part = (float*)((char*)d_ws + off);
    size_t part_bytes = (size_t)M * O * sizeof(float);
    bool splitk = (ws_size >= off + part_bytes);

    int n_x = M * I;
    cvt_f32_f16_kernel<<<(n_x / 4 + 255) / 256, 256, 0, stream>>>(
        x, xh, n_x, codebook, c2);
    pq_quant_kernel<<<n_groups / 256, 256, 0, stream>>>(
        weight, codebook, c2, rowscale, wq, I / D);

    if (splitk) {
        gemm_f16_kernel<<<dim3(O / TILE, M / TILE, 2), 256, 0, stream>>>(
            xh, wq, bias, out, part, M, O, I, I / 2);
        reduce_add_kernel<<<(M * O / 4 + 255) / 256, 256, 0, stream>>>(
            out, part, M * O);
    } else {
        gemm_f16_kernel<<<dim3(O / TILE, M / TILE, 1), 256, 0, stream>>>(
            xh, wq, bias, out, part, M, O, I, I);
    }
}